// Round 11
// baseline (41.402 us; speedup 1.0000x reference)
//
#include <hip/hip_runtime.h>
#include <math.h>

// GAT: B=32, N=1024, F=64, H=3, D=16
constexpr int Bc = 32, Nn = 1024, Fc = 64, Hc = 3, Dc = 16;
constexpr float ALPHAc = 0.2f;
constexpr float L2E    = 1.44269504088896340736f;

__device__ __forceinline__ unsigned enc_f32(float x) {
    unsigned b = __builtin_bit_cast(unsigned, x);
    return (b & 0x80000000u) ? ~b : (b | 0x80000000u);
}
__device__ __forceinline__ float dec_f32(unsigned e) {
    unsigned b = (e & 0x80000000u) ? (e ^ 0x80000000u) : ~e;
    return __builtin_bit_cast(float, b);
}

// DPP-based inclusive wave(64) scan: row_shr 1/2/4/8 then row_bcast 15/31.
template <int CTRL, int RMASK, bool BC>
__device__ __forceinline__ float dpp_acc(float x) {
    int s = __builtin_amdgcn_update_dpp(0, __builtin_bit_cast(int, x),
                                        CTRL, RMASK, 0xF, BC);
    return x + __builtin_bit_cast(float, s);
}
__device__ __forceinline__ float wave_incl_scan(float x) {
    x = dpp_acc<0x111, 0xF, true >(x);   // row_shr:1
    x = dpp_acc<0x112, 0xF, true >(x);   // row_shr:2
    x = dpp_acc<0x114, 0xF, true >(x);   // row_shr:4
    x = dpp_acc<0x118, 0xF, true >(x);   // row_shr:8
    x = dpp_acc<0x142, 0xa, false>(x);   // row_bcast:15 -> rows 1,3
    x = dpp_acc<0x143, 0xc, false>(x);   // row_bcast:31 -> rows 2,3
    return x;
}

// ---------------------------------------------------------------------------
// Grid = 384: block gid = bh*4 + q handles (b,h)=bh, output dims q*4..q*4+3.
// 10 scan channels per block: (B*Wh[4], D*Wh[4], B, D). 78.6 KB LDS ->
// 2 blocks/CU, 32 waves/CU; all 256 CUs busy.
//  P-1: rows [gid*3, gid*3+3) -> magic rowful flags (self-validating).
//  P0 : full 64x16 GEMM per thread (for s1,s2); slice -> whs LDS.
//  P1 : hybrid bitonic sort of u32 keys (22b trunc s2 | 10b idx) [R9 verbatim].
//  P2 : v[10]; DPP wave scan + 16-wide offset scan -> PS[1025][11] LDS.
//  P3 : row i=t: spin flag; binary search; combine slice; fallback on whs.
// ---------------------------------------------------------------------------
__global__ __launch_bounds__(1024, 8) void gat_one(
    const float* __restrict__ hbuf, const float* __restrict__ W,
    const float* __restrict__ a, const float* __restrict__ adj,
    unsigned* __restrict__ rowful, float* __restrict__ out)
{
    // 45,100 + 8,192 + 4,096 + 20,480 + 640 + 64 = 78,572 B LDS
    __shared__ __align__(16) float    PS[1025 * 11];
    __shared__ __align__(16) unsigned skA[Nn], skB[Nn];
    __shared__ __align__(16) float    s2o[Nn];
    __shared__ __align__(16) float    whs[Nn][5];   // slice Wh + pad
    __shared__ float    wtot[16][10];
    __shared__ unsigned wmiss[16];

    int gid = blockIdx.x;
    int bh  = gid >> 2, q = gid & 3;
    int hh  = bh % Hc,  b = bh / Hc;
    int t   = threadIdx.x;           // n in P0; key slot in P1/P2; row i in P3
    int wv  = t >> 6, lane = t & 63;

    // ---------------- P-1: rowful chunk (rows gid*3 .. gid*3+2) ----------
    int row0 = gid * 3;
    unsigned miss = 0;
#pragma unroll
    for (int rr = 0; rr < 3; ++rr) {
        int row = row0 + rr;
        if (row < Nn) {
            float av = adj[(size_t)row * Nn + t];   // coalesced across t
            miss |= (av > 0.f) ? 0u : (1u << rr);
        }
    }
#pragma unroll
    for (int off = 1; off < 64; off <<= 1)
        miss |= (unsigned)__shfl_xor((int)miss, off, 64);
    if (lane == 0) wmiss[wv] = miss;
    __syncthreads();
    if (t < 3) {
        int row = row0 + t;
        if (row < Nn) {
            unsigned m = 0;
#pragma unroll
            for (int w2 = 0; w2 < 16; ++w2) m |= wmiss[w2];
            unsigned full = ((m >> t) & 1u) ^ 1u;
            unsigned val  = 0x5AFE0000u | ((unsigned)row << 1) | full;
            __hip_atomic_store(&rowful[row], val, __ATOMIC_RELAXED,
                               __HIP_MEMORY_SCOPE_AGENT);
        }
    }

    // ---------------- P0: Wh (full, for s1/s2), slice -> LDS ----------------
    const float4* h4 = (const float4*)(hbuf + ((size_t)b * Nn + t) * Fc);
    const float*  Wp = W + (size_t)hh * Fc * Dc;

    float acc[Dc];
#pragma unroll
    for (int d = 0; d < Dc; ++d) acc[d] = 0.f;

#pragma unroll
    for (int qq = 0; qq < Fc / 4; ++qq) {
        float4 hv = h4[qq];
#pragma unroll
        for (int c = 0; c < 4; ++c) {
            float hv1 = (c == 0) ? hv.x : (c == 1) ? hv.y : (c == 2) ? hv.z : hv.w;
            const float4* wrp = (const float4*)(Wp + (4 * qq + c) * Dc);
#pragma unroll
            for (int u = 0; u < 4; ++u) {
                float4 wq = wrp[u];
                acc[4*u+0] = fmaf(hv1, wq.x, acc[4*u+0]);
                acc[4*u+1] = fmaf(hv1, wq.y, acc[4*u+1]);
                acc[4*u+2] = fmaf(hv1, wq.z, acc[4*u+2]);
                acc[4*u+3] = fmaf(hv1, wq.w, acc[4*u+3]);
            }
        }
    }

    // slice q -> LDS (padded stride 5)
#pragma unroll
    for (int c = 0; c < 4; ++c)
        whs[t][c] = acc[q * 4 + c];

    const float* ap = a + (size_t)hh * 2 * Dc;
    float s1v = 0.f, s2v = 0.f;
#pragma unroll
    for (int d = 0; d < Dc; ++d) {
        s1v = fmaf(acc[d], ap[d],      s1v);
        s2v = fmaf(acc[d], ap[Dc + d], s2v);
    }
    s2o[t] = s2v;                    // exact s2 (fallback path only)

    // ---------------- P1: hybrid bitonic sort (u32 keys) [R9 verbatim] -----
    unsigned key = (enc_f32(s2v) & ~1023u) | (unsigned)t;

#pragma unroll
    for (int k = 2; k <= 64; k <<= 1) {
#pragma unroll
        for (int s = k >> 1; s >= 1; s >>= 1) {
            unsigned other = (unsigned)__shfl_xor((int)key, s, 64);
            bool dirUp = ((t & k) == 0);
            bool lower = ((lane & s) == 0);
            unsigned mn = key < other ? key : other;
            unsigned mx = key < other ? other : key;
            key = (lower == dirUp) ? mn : mx;
        }
    }
    unsigned* bufs[2] = {skA, skB};
    int pb = 0;
#pragma unroll
    for (int k = 128; k <= 1024; k <<= 1) {
#pragma unroll
        for (int s = k >> 1; s >= 64; s >>= 1) {
            bufs[pb][t] = key;
            __syncthreads();
            unsigned other = bufs[pb][t ^ s];
            bool dirUp = ((t & k) == 0);
            bool lower = ((t & s) == 0);
            unsigned mn = key < other ? key : other;
            unsigned mx = key < other ? other : key;
            key = (lower == dirUp) ? mn : mx;
            pb ^= 1;
        }
#pragma unroll
        for (int s = 32; s >= 1; s >>= 1) {
            unsigned other = (unsigned)__shfl_xor((int)key, s, 64);
            bool dirUp = ((t & k) == 0);
            bool lower = ((lane & s) == 0);
            unsigned mn = key < other ? key : other;
            unsigned mx = key < other ? other : key;
            key = (lower == dirUp) ? mn : mx;
        }
    }
    unsigned* sorted = bufs[pb];
    sorted[t] = key;                 // read in P3, behind P2's barriers

    // ---------------- P2: v[10] + block exclusive scan -> PS ----------------
    int   j  = key & 1023u;
    float sv = dec_f32((key & ~1023u) | 512u);   // trunc s2 + half-LSB center
    float Bv = __builtin_amdgcn_exp2f(sv * L2E);
    float Dv = __builtin_amdgcn_exp2f(sv * (ALPHAc * L2E));
    float w0 = whs[j][0], w1 = whs[j][1], w2 = whs[j][2], w3 = whs[j][3];

    float v[10] = {Bv * w0, Bv * w1, Bv * w2, Bv * w3,
                   Dv * w0, Dv * w1, Dv * w2, Dv * w3, Bv, Dv};

    // DPP inclusive scan per channel (pure VALU), exclusive via subtract
#pragma unroll
    for (int c = 0; c < 10; ++c) {
        float inc = wave_incl_scan(v[c]);
        if (lane == 63) wtot[wv][c] = inc;     // inclusive wave total
        v[c] = inc - v[c];                     // exclusive within wave
    }
    __syncthreads();

    // parallel wave-offset scan: thread (c,w) = t = c*16 + w, 16-wide shfl
    if (t < 160) {
        int c = t >> 4, w = t & 15;
        float own = wtot[w][c];
        float x = own;
#pragma unroll
        for (int off = 1; off < 16; off <<= 1) {
            float o = __shfl_up(x, off, 16);
            if ((lane & 15) >= off) x += o;
        }
        wtot[w][c] = x - own;                  // exclusive wave offset
        if (w == 15) PS[(size_t)1024 * 11 + c] = x;   // grand totals
    }
    __syncthreads();

    float* myrow = PS + (size_t)t * 11;        // stride 11 -> conflict-free
#pragma unroll
    for (int c = 0; c < 10; ++c)
        myrow[c] = v[c] + wtot[wv][c];
    __syncthreads();

    // ---------------- P3: combine (slice q) ----------------
    int i = t;
    float R  = __builtin_amdgcn_exp2f(-0.8f * L2E * s1v);
    float* op = out + ((size_t)b * Nn + i) * (Hc * Dc) + hh * Dc + q * 4;

    // spin-load self-validating flag (writers all co-resident: 384 <= 512)
    unsigned expv = 0x5AFE0000u | ((unsigned)i << 1) | 1u;
    unsigned fv;
    do {
        fv = __hip_atomic_load(&rowful[i], __ATOMIC_RELAXED,
                               __HIP_MEMORY_SCOPE_AGENT);
    } while ((fv | 1u) != expv);

    if (fv & 1u) {
        unsigned qk = (enc_f32(-s1v) & ~1023u) | 1023u;
        int p = 0;
#pragma unroll
        for (int step = 512; step >= 1; step >>= 1)
            if (sorted[p + step - 1] <= qk) p += step;   // p = #{keys <= qk}

        const float* Pp = PS + (size_t)p * 11;
        const float* Tp = PS + (size_t)1024 * 11;
        float den = (Tp[8] - Pp[8]) + R * Pp[9];
        float inv = 1.0f / den;
        float o0 = ((Tp[0] - Pp[0]) + R * Pp[4]) * inv;
        float o1 = ((Tp[1] - Pp[1]) + R * Pp[5]) * inv;
        float o2 = ((Tp[2] - Pp[2]) + R * Pp[6]) * inv;
        float o3 = ((Tp[3] - Pp[3]) + R * Pp[7]) * inv;
        *(float4*)op = make_float4(o0, o1, o2, o3);
    } else {
        // exact fallback for masked rows (dead when adj is all-positive)
        float num[4] = {0.f, 0.f, 0.f, 0.f};
        float den = 0.f;
        for (int jj = 0; jj < Nn; ++jj) {
            float aq = adj[(size_t)i * Nn + jj];
            if (aq > 0.f) {
                float sq = s2o[jj];
                float Bq = __builtin_amdgcn_exp2f(sq * L2E);
                float Dq = __builtin_amdgcn_exp2f(sq * (ALPHAc * L2E));
                float w_ = fmaxf(Bq, R * Dq);
                den += w_;
#pragma unroll
                for (int c = 0; c < 4; ++c)
                    num[c] = fmaf(w_, whs[jj][c], num[c]);
            }
        }
        float inv = 1.0f / den;
        *(float4*)op = make_float4(num[0]*inv, num[1]*inv, num[2]*inv, num[3]*inv);
    }
}

// ---------------------------------------------------------------------------
extern "C" void kernel_launch(void* const* d_in, const int* in_sizes, int n_in,
                              void* d_out, int out_size, void* d_ws, size_t ws_size,
                              hipStream_t stream)
{
    const float* hbuf = (const float*)d_in[0];   // (B,N,F)
    const float* adj  = (const float*)d_in[1];   // (N,N)
    const float* W    = (const float*)d_in[2];   // (H,F,D)
    const float* a    = (const float*)d_in[3];   // (H,2D,1)
    float* out = (float*)d_out;                  // (B,N,H*D) fp32

    // ws: rowful magic flags only (1024 u32)
    unsigned* rowful = (unsigned*)d_ws;

    gat_one<<<dim3(Bc * Hc * 4), dim3(1024), 0, stream>>>(
        hbuf, W, a, adj, rowful, out);
}

// Round 12
// 36.656 us; speedup vs baseline: 1.1295x; 1.1295x over previous
//
#include <hip/hip_runtime.h>
#include <math.h>

// GAT: B=32, N=1024, F=64, H=3, D=16
constexpr int Bc = 32, Nn = 1024, Fc = 64, Hc = 3, Dc = 16;
constexpr float ALPHAc = 0.2f;
constexpr float L2E    = 1.44269504088896340736f;

__device__ __forceinline__ unsigned enc_f32(float x) {
    unsigned b = __builtin_bit_cast(unsigned, x);
    return (b & 0x80000000u) ? ~b : (b | 0x80000000u);
}
__device__ __forceinline__ float dec_f32(unsigned e) {
    unsigned b = (e & 0x80000000u) ? (e ^ 0x80000000u) : ~e;
    return __builtin_bit_cast(float, b);
}

// DPP-based inclusive wave(64) scan: row_shr 1/2/4/8 then row_bcast 15/31.
template <int CTRL, int RMASK, bool BC>
__device__ __forceinline__ float dpp_acc(float x) {
    int s = __builtin_amdgcn_update_dpp(0, __builtin_bit_cast(int, x),
                                        CTRL, RMASK, 0xF, BC);
    return x + __builtin_bit_cast(float, s);
}
__device__ __forceinline__ float wave_incl_scan(float x) {
    x = dpp_acc<0x111, 0xF, true >(x);   // row_shr:1
    x = dpp_acc<0x112, 0xF, true >(x);   // row_shr:2
    x = dpp_acc<0x114, 0xF, true >(x);   // row_shr:4
    x = dpp_acc<0x118, 0xF, true >(x);   // row_shr:8
    x = dpp_acc<0x142, 0xa, false>(x);   // row_bcast:15 -> rows 1,3
    x = dpp_acc<0x143, 0xc, false>(x);   // row_bcast:31 -> rows 2,3
    return x;
}

// lane XOR exchange; s=1,2 via quad_perm DPP (VALU), else shfl (LDS pipe).
__device__ __forceinline__ unsigned lane_xor(unsigned x, int s) {
    if (s == 1)
        return (unsigned)__builtin_amdgcn_update_dpp(0, (int)x, 0xB1, 0xF, 0xF, true);
    if (s == 2)
        return (unsigned)__builtin_amdgcn_update_dpp(0, (int)x, 0x4E, 0xF, 0xF, true);
    return (unsigned)__shfl_xor((int)x, s, 64);
}

// ---------------------------------------------------------------------------
// Grid = 384. XCD-cluster remap: physical p -> (b,h,q) such that all 12
// sibling blocks of a batch b land on one XCD (p%8 round-robin heuristic;
// correctness-neutral bijection). Block handles (b,h), output dims q*4..+3.
//  P-1: blocks p<256 scan adj rows p*4..p*4+3 -> magic rowful flags.
//  P0 : full 64x16 GEMM per thread, h loaded in 4 prefetched float4-chunks;
//       slice q -> whs4 LDS (float4); s1,s2.
//  P1 : hybrid bitonic sort of u32 keys; s=1,2 stages via quad_perm DPP.
//  P2 : v[10]; DPP wave scan + 16-wide offset scan -> PS[1025][11] LDS.
//  P3 : row i=t: spin flag; binary search; combine slice; fallback on whs4.
// ---------------------------------------------------------------------------
__global__ __launch_bounds__(1024, 8) void gat_one(
    const float* __restrict__ hbuf, const float* __restrict__ W,
    const float* __restrict__ a, const float* __restrict__ adj,
    unsigned* __restrict__ rowful, float* __restrict__ out)
{
    // 45,100 + 8,192 + 4,096 + 16,384 + 640 + 64 = 74,476 B LDS (2 blocks/CU)
    __shared__ __align__(16) float    PS[1025 * 11];
    __shared__ __align__(16) unsigned skA[Nn], skB[Nn];
    __shared__ __align__(16) float    s2o[Nn];
    __shared__ __align__(16) float4   whs4[Nn];     // slice Wh (4 dims)
    __shared__ float    wtot[16][10];
    __shared__ unsigned wmiss[16];

    int p  = blockIdx.x;
    int xq = p & 7, m = p >> 3;                 // XCD, slot-on-XCD
    int b  = xq + 8 * (m / 12);                 // 4 b's per XCD, clustered
    int hq = m % 12;
    int hh = hq >> 2, q = hq & 3;
    int bh = b * Hc + hh;
    int t  = threadIdx.x;            // n in P0; key slot in P1/P2; row i in P3
    int wv = t >> 6, lane = t & 63;
    (void)bh;

    // ---------------- P-1: rowful rows p*4..p*4+3 (blocks p<256 only) ------
    if (p < 256) {                               // block-uniform branch
        unsigned miss = 0;
#pragma unroll
        for (int rr = 0; rr < 4; ++rr) {
            float av = adj[(size_t)(p * 4 + rr) * Nn + t];   // coalesced
            miss |= (av > 0.f) ? 0u : (1u << rr);
        }
#pragma unroll
        for (int off = 1; off < 64; off <<= 1)
            miss |= (unsigned)__shfl_xor((int)miss, off, 64);
        if (lane == 0) wmiss[wv] = miss;
        __syncthreads();
        if (t < 4) {
            unsigned mm = 0;
#pragma unroll
            for (int w2 = 0; w2 < 16; ++w2) mm |= wmiss[w2];
            int row = p * 4 + t;
            unsigned full = ((mm >> t) & 1u) ^ 1u;
            unsigned val  = 0x5AFE0000u | ((unsigned)row << 1) | full;
            __hip_atomic_store(&rowful[row], val, __ATOMIC_RELAXED,
                               __HIP_MEMORY_SCOPE_AGENT);
        }
    }

    // ---------------- P0: GEMM with prefetched h-chunks ----------------
    const float4* h4 = (const float4*)(hbuf + ((size_t)b * Nn + t) * Fc);
    const float*  Wp = W + (size_t)hh * Fc * Dc;

    float acc[Dc];
#pragma unroll
    for (int d = 0; d < Dc; ++d) acc[d] = 0.f;

    float4 cA[4];
#pragma unroll
    for (int u = 0; u < 4; ++u) cA[u] = h4[u];           // chunk 0 in flight

#pragma unroll
    for (int ch = 0; ch < 4; ++ch) {
        float4 cB[4];
        if (ch < 3) {
#pragma unroll
            for (int u = 0; u < 4; ++u) cB[u] = h4[4 * (ch + 1) + u];
        }
#pragma unroll
        for (int u = 0; u < 4; ++u) {
            float4 hv = cA[u];
#pragma unroll
            for (int c = 0; c < 4; ++c) {
                float hv1 = (c == 0) ? hv.x : (c == 1) ? hv.y
                          : (c == 2) ? hv.z : hv.w;
                int f = ch * 16 + u * 4 + c;
                const float4* wrp = (const float4*)(Wp + f * Dc);   // uniform
#pragma unroll
                for (int w = 0; w < 4; ++w) {
                    float4 wq = wrp[w];
                    acc[4*w+0] = fmaf(hv1, wq.x, acc[4*w+0]);
                    acc[4*w+1] = fmaf(hv1, wq.y, acc[4*w+1]);
                    acc[4*w+2] = fmaf(hv1, wq.z, acc[4*w+2]);
                    acc[4*w+3] = fmaf(hv1, wq.w, acc[4*w+3]);
                }
            }
        }
        if (ch < 3) {
#pragma unroll
            for (int u = 0; u < 4; ++u) cA[u] = cB[u];
        }
    }

    whs4[t] = make_float4(acc[q*4+0], acc[q*4+1], acc[q*4+2], acc[q*4+3]);

    const float* ap = a + (size_t)hh * 2 * Dc;
    float s1v = 0.f, s2v = 0.f;
#pragma unroll
    for (int d = 0; d < Dc; ++d) {
        s1v = fmaf(acc[d], ap[d],      s1v);
        s2v = fmaf(acc[d], ap[Dc + d], s2v);
    }
    s2o[t] = s2v;                    // exact s2 (fallback path only)

    // ---------------- P1: hybrid bitonic sort (u32 keys) ----------------
    unsigned key = (enc_f32(s2v) & ~1023u) | (unsigned)t;

    // wave-local stages (k=2..64): registers; s=1,2 via quad_perm DPP
#pragma unroll
    for (int k = 2; k <= 64; k <<= 1) {
#pragma unroll
        for (int s = k >> 1; s >= 1; s >>= 1) {
            unsigned other = lane_xor(key, s);
            bool dirUp = ((t & k) == 0);
            bool lower = ((lane & s) == 0);
            unsigned mn = key < other ? key : other;
            unsigned mx = key < other ? other : key;
            key = (lower == dirUp) ? mn : mx;
        }
    }
    // cross-wave merges: s>=64 double-buffered LDS (1 barrier/stage)
    unsigned* bufs[2] = {skA, skB};
    int pb = 0;
#pragma unroll
    for (int k = 128; k <= 1024; k <<= 1) {
#pragma unroll
        for (int s = k >> 1; s >= 64; s >>= 1) {
            bufs[pb][t] = key;
            __syncthreads();
            unsigned other = bufs[pb][t ^ s];
            bool dirUp = ((t & k) == 0);
            bool lower = ((t & s) == 0);
            unsigned mn = key < other ? key : other;
            unsigned mx = key < other ? other : key;
            key = (lower == dirUp) ? mn : mx;
            pb ^= 1;
        }
#pragma unroll
        for (int s = 32; s >= 1; s >>= 1) {
            unsigned other = lane_xor(key, s);
            bool dirUp = ((t & k) == 0);
            bool lower = ((lane & s) == 0);
            unsigned mn = key < other ? key : other;
            unsigned mx = key < other ? other : key;
            key = (lower == dirUp) ? mn : mx;
        }
    }
    unsigned* sorted = bufs[pb];
    sorted[t] = key;                 // read in P3, behind P2's barriers

    // ---------------- P2: v[10] + block exclusive scan -> PS ----------------
    int   j  = key & 1023u;
    float sv = dec_f32((key & ~1023u) | 512u);   // trunc s2 + half-LSB center
    float Bv = __builtin_amdgcn_exp2f(sv * L2E);
    float Dv = __builtin_amdgcn_exp2f(sv * (ALPHAc * L2E));
    float4 wsl = whs4[j];                        // one b128 gather

    float v[10] = {Bv * wsl.x, Bv * wsl.y, Bv * wsl.z, Bv * wsl.w,
                   Dv * wsl.x, Dv * wsl.y, Dv * wsl.z, Dv * wsl.w, Bv, Dv};

    // DPP inclusive scan per channel (pure VALU), exclusive via subtract
#pragma unroll
    for (int c = 0; c < 10; ++c) {
        float inc = wave_incl_scan(v[c]);
        if (lane == 63) wtot[wv][c] = inc;     // inclusive wave total
        v[c] = inc - v[c];                     // exclusive within wave
    }
    __syncthreads();

    // parallel wave-offset scan: thread (c,w) = t = c*16 + w, 16-wide shfl
    if (t < 160) {
        int c = t >> 4, w = t & 15;
        float own = wtot[w][c];
        float x = own;
#pragma unroll
        for (int off = 1; off < 16; off <<= 1) {
            float o = __shfl_up(x, off, 16);
            if ((lane & 15) >= off) x += o;
        }
        wtot[w][c] = x - own;                  // exclusive wave offset
        if (w == 15) PS[(size_t)1024 * 11 + c] = x;   // grand totals
    }
    __syncthreads();

    float* myrow = PS + (size_t)t * 11;        // stride 11 -> conflict-free
#pragma unroll
    for (int c = 0; c < 10; ++c)
        myrow[c] = v[c] + wtot[wv][c];
    __syncthreads();

    // ---------------- P3: combine (slice q) ----------------
    int i = t;
    float R  = __builtin_amdgcn_exp2f(-0.8f * L2E * s1v);
    float* op = out + ((size_t)b * Nn + i) * (Hc * Dc) + hh * Dc + q * 4;

    // spin-load self-validating flag (writers = first-dispatched 256 blocks;
    // 2 blocks/CU capacity = 512 >= 384 -> all co-resident, no deadlock)
    unsigned expv = 0x5AFE0000u | ((unsigned)i << 1) | 1u;
    unsigned fv;
    do {
        fv = __hip_atomic_load(&rowful[i], __ATOMIC_RELAXED,
                               __HIP_MEMORY_SCOPE_AGENT);
    } while ((fv | 1u) != expv);

    if (fv & 1u) {
        unsigned qk = (enc_f32(-s1v) & ~1023u) | 1023u;
        int pp = 0;
#pragma unroll
        for (int step = 512; step >= 1; step >>= 1)
            if (sorted[pp + step - 1] <= qk) pp += step;   // #{keys <= qk}

        const float* Pp = PS + (size_t)pp * 11;
        const float* Tp = PS + (size_t)1024 * 11;
        float den = (Tp[8] - Pp[8]) + R * Pp[9];
        float inv = 1.0f / den;
        float o0 = ((Tp[0] - Pp[0]) + R * Pp[4]) * inv;
        float o1 = ((Tp[1] - Pp[1]) + R * Pp[5]) * inv;
        float o2 = ((Tp[2] - Pp[2]) + R * Pp[6]) * inv;
        float o3 = ((Tp[3] - Pp[3]) + R * Pp[7]) * inv;
        *(float4*)op = make_float4(o0, o1, o2, o3);
    } else {
        // exact fallback for masked rows (dead when adj is all-positive)
        float num[4] = {0.f, 0.f, 0.f, 0.f};
        float den = 0.f;
        for (int jj = 0; jj < Nn; ++jj) {
            float aq = adj[(size_t)i * Nn + jj];
            if (aq > 0.f) {
                float sq = s2o[jj];
                float Bq = __builtin_amdgcn_exp2f(sq * L2E);
                float Dq = __builtin_amdgcn_exp2f(sq * (ALPHAc * L2E));
                float w_ = fmaxf(Bq, R * Dq);
                den += w_;
                float4 ws = whs4[jj];
                num[0] = fmaf(w_, ws.x, num[0]);
                num[1] = fmaf(w_, ws.y, num[1]);
                num[2] = fmaf(w_, ws.z, num[2]);
                num[3] = fmaf(w_, ws.w, num[3]);
            }
        }
        float inv = 1.0f / den;
        *(float4*)op = make_float4(num[0]*inv, num[1]*inv, num[2]*inv, num[3]*inv);
    }
}

// ---------------------------------------------------------------------------
extern "C" void kernel_launch(void* const* d_in, const int* in_sizes, int n_in,
                              void* d_out, int out_size, void* d_ws, size_t ws_size,
                              hipStream_t stream)
{
    const float* hbuf = (const float*)d_in[0];   // (B,N,F)
    const float* adj  = (const float*)d_in[1];   // (N,N)
    const float* W    = (const float*)d_in[2];   // (H,F,D)
    const float* a    = (const float*)d_in[3];   // (H,2D,1)
    float* out = (float*)d_out;                  // (B,N,H*D) fp32

    // ws: rowful magic flags only (1024 u32)
    unsigned* rowful = (unsigned*)d_ws;

    gat_one<<<dim3(Bc * Hc * 4), dim3(1024), 0, stream>>>(
        hbuf, W, a, adj, rowful, out);
}